// Round 1
// baseline (1256.846 us; speedup 1.0000x reference)
//
#include <hip/hip_runtime.h>
#include <hip/hip_bf16.h>

#define B_ 8
#define C_ 64
#define N_ 4096
#define K_ 20
#define O_ 64

constexpr float BN_EPS = 1e-5f;
constexpr float NEG = 0.2f;
constexpr int ROWS = B_ * N_;        // 32768
constexpr int M_TOT = ROWS * K_;     // 655360

// ----------------------------------------------------------------------------
// ws layout (float elements):
//   y   : [0,        2097152)   y[b][n][o]  = xt[b,n,:]  . W1[o,:]
//   z   : [2097152,  4194304)   z[b][n][o]  = xt[b,n,:]  . (W2-W1)[o,:]
//   xx  : [4194304,  4227072)   xx[b][n]    = ||xt[b,n,:]||^2
//   idx : [4227072,  4882432)   (int) idx[b][n][k]
//   s1  : [4882432,  4882496)   sum h   per o
//   s2  : [4882496,  4882560)   sum h^2 per o
//   sc  : [4882560,  4882624)   BN scale per o
//   sh  : [4882624,  4882688)   BN shift per o
// total ~19.5 MB
// ----------------------------------------------------------------------------

__global__ __launch_bounds__(256) void prep_kernel(const float* __restrict__ x,
                                                   const float* __restrict__ W,
                                                   float* __restrict__ y,
                                                   float* __restrict__ z,
                                                   float* __restrict__ xx) {
  __shared__ float xt[64][65];  // [n_local][c]
  __shared__ float w1[64][65];  // [o][c]   = W[o][c]
  __shared__ float wd[64][65];  // [o][c]   = W[o][64+c] - W[o][c]
  const int b = blockIdx.x >> 6;
  const int n0 = (blockIdx.x & 63) << 6;
  const int tid = threadIdx.x;

  for (int rep = 0; rep < 16; ++rep) {
    int id = rep * 256 + tid;
    int cc = id >> 6, nl = id & 63;
    xt[nl][cc] = x[((b * 64 + cc) << 12) + n0 + nl];  // coalesced over nl
    int o = cc, c = nl;
    float a = W[o * 128 + c];
    float bb = W[o * 128 + 64 + c];
    w1[o][c] = a;
    wd[o][c] = bb - a;
  }
  __syncthreads();

  const int o = tid & 63;
  for (int nl = tid >> 6; nl < 64; nl += 4) {
    float ay = 0.f, az = 0.f;
#pragma unroll 8
    for (int c = 0; c < 64; ++c) {
      float v = xt[nl][c];
      ay = fmaf(v, w1[o][c], ay);
      az = fmaf(v, wd[o][c], az);
    }
    int gi = (((b << 12) + n0 + nl) << 6) + o;
    y[gi] = ay;
    z[gi] = az;
  }
  if (tid < 64) {
    float s = 0.f;
#pragma unroll 8
    for (int c = 0; c < 64; ++c) {
      float v = xt[tid][c];
      s = fmaf(v, v, s);
    }
    xx[(b << 12) + n0 + tid] = s;
  }
}

// One wave per query row i. Streaming top-20 (smallest d = xx[j] - 2*<xi,xj>,
// which orders identically to the reference's xx[i]+xx[j]-2*<xi,xj>).
// Buffer lives in registers of lanes 0..19; insert is wave-cooperative.
__global__ __launch_bounds__(256) void knn_kernel(const float* __restrict__ x,
                                                  const float* __restrict__ xx,
                                                  int* __restrict__ idx) {
  const int w = threadIdx.x >> 6;
  const int lane = threadIdx.x & 63;
  const int row = blockIdx.x * 4 + w;
  const int b = row >> 12;
  const int i = row & 4095;

  __shared__ float xi_s[4][64];
  const float* xb = x + ((size_t)b << 18);  // b*64*4096
  xi_s[w][lane] = xb[(lane << 12) + i];     // xi[c] for c = lane
  __syncthreads();

  float bv = (lane < K_) ? __builtin_inff() : -__builtin_inff();
  int bi = 0;
  float T = __builtin_inff();
  const float* xxb = xx + (b << 12);

  for (int jb = 0; jb < N_; jb += 256) {
    const int j0 = jb + (lane << 2);
    float4 acc = make_float4(0.f, 0.f, 0.f, 0.f);
    const float* xp = xb + j0;
#pragma unroll 8
    for (int c = 0; c < 64; ++c) {
      float xic = xi_s[w][c];
      float4 xj = *(const float4*)(xp + ((size_t)c << 12));
      acc.x = fmaf(xic, xj.x, acc.x);
      acc.y = fmaf(xic, xj.y, acc.y);
      acc.z = fmaf(xic, xj.z, acc.z);
      acc.w = fmaf(xic, xj.w, acc.w);
    }
    float4 xxj = *(const float4*)(xxb + j0);
    float dv[4] = {xxj.x - 2.f * acc.x, xxj.y - 2.f * acc.y,
                   xxj.z - 2.f * acc.z, xxj.w - 2.f * acc.w};
#pragma unroll
    for (int jj = 0; jj < 4; ++jj) {
      float v = dv[jj];
      unsigned long long m = __ballot(v < T);
      while (m) {
        int src = __ffsll(m) - 1;
        m &= m - 1;
        float cv = __shfl(v, src);
        int cj = __shfl(j0 + jj, src);
        // current max of buffer (lanes >= K_ contribute -inf)
        float M = bv;
#pragma unroll
        for (int off = 32; off; off >>= 1) M = fmaxf(M, __shfl_xor(M, off));
        if (cv < M) {
          unsigned long long mm = __ballot(bv == M);
          int slot = __ffsll(mm) - 1;
          if (lane == slot) {
            bv = cv;
            bi = cj;
          }
          float M2 = bv;
#pragma unroll
          for (int off = 32; off; off >>= 1) M2 = fmaxf(M2, __shfl_xor(M2, off));
          T = M2;
        } else {
          T = M;
        }
      }
    }
  }
  if (lane < K_) idx[row * K_ + lane] = bi;
}

__global__ __launch_bounds__(256) void stats_kernel(const float* __restrict__ y,
                                                    const float* __restrict__ z,
                                                    const int* __restrict__ idx,
                                                    float* __restrict__ s1,
                                                    float* __restrict__ s2) {
  const int tid = threadIdx.x;
  const int o = tid & 63;
  const int r = tid >> 6;
  const int row0 = blockIdx.x << 6;  // 64 rows per block
  float a1 = 0.f, a2 = 0.f;
  for (int rl = r; rl < 64; rl += 4) {
    const int row = row0 + rl;
    const int b = row >> 12;
    const float zv = z[(row << 6) + o];
    const int* ip = idx + row * K_;
    const float* yb = y + ((size_t)b << 18);
    float s1r = 0.f;
#pragma unroll
    for (int k = 0; k < K_; ++k) {
      int j = ip[k];
      float h = yb[(j << 6) + o] + zv;
      s1r += h;
      a2 = fmaf(h, h, a2);
    }
    a1 += s1r;
  }
  __shared__ float r1[4][64];
  __shared__ float r2[4][64];
  r1[r][o] = a1;
  r2[r][o] = a2;
  __syncthreads();
  if (tid < 64) {
    float t1 = r1[0][tid] + r1[1][tid] + r1[2][tid] + r1[3][tid];
    float t2 = r2[0][tid] + r2[1][tid] + r2[2][tid] + r2[3][tid];
    atomicAdd(&s1[tid], t1);
    atomicAdd(&s2[tid], t2);
  }
}

__global__ void finalize_kernel(const float* __restrict__ s1,
                                const float* __restrict__ s2,
                                const float* __restrict__ gamma,
                                const float* __restrict__ beta,
                                float* __restrict__ sc,
                                float* __restrict__ sh) {
  int o = threadIdx.x;
  float mean = s1[o] / (float)M_TOT;
  float var = s2[o] / (float)M_TOT - mean * mean;
  float inv = 1.0f / sqrtf(var + BN_EPS);
  float s = gamma[o] * inv;
  sc[o] = s;
  sh[o] = beta[o] - mean * s;
}

__global__ __launch_bounds__(256) void out_kernel(const float* __restrict__ y,
                                                  const float* __restrict__ z,
                                                  const int* __restrict__ idx,
                                                  const float* __restrict__ sc,
                                                  const float* __restrict__ sh,
                                                  float* __restrict__ out) {
  __shared__ float til[64][65];  // [o][n_local]
  const int tid = threadIdx.x;
  const int b = blockIdx.x >> 6;
  const int n0 = (blockIdx.x & 63) << 6;
  const int o = tid & 63;
  const float s = sc[o];
  const float t = sh[o];
  const float* yb = y + ((size_t)b << 18);

  for (int nl = tid >> 6; nl < 64; nl += 4) {
    const int row = (b << 12) + n0 + nl;
    const float zv = z[(row << 6) + o];
    const int* ip = idx + row * K_;
    float m = -__builtin_inff();
#pragma unroll
    for (int k = 0; k < K_; ++k) {
      int j = ip[k];
      float h = yb[(j << 6) + o] + zv;
      float hn = fmaf(h, s, t);
      float a = hn >= 0.f ? hn : NEG * hn;
      m = fmaxf(m, a);
    }
    til[o][nl] = m;
  }
  __syncthreads();
  for (int rep = 0; rep < 16; ++rep) {
    int id = rep * 256 + tid;
    int oo = id >> 6, nl = id & 63;
    out[((size_t)((b << 6) + oo) << 12) + n0 + nl] = til[oo][nl];
  }
}

extern "C" void kernel_launch(void* const* d_in, const int* in_sizes, int n_in,
                              void* d_out, int out_size, void* d_ws, size_t ws_size,
                              hipStream_t stream) {
  const float* x = (const float*)d_in[0];
  const float* W = (const float*)d_in[1];
  const float* gamma = (const float*)d_in[2];
  const float* beta = (const float*)d_in[3];
  float* ws = (float*)d_ws;
  float* y = ws;
  float* z = ws + 2097152;
  float* xx = ws + 4194304;
  int* idxp = (int*)(ws + 4227072);
  float* s1 = ws + 4882432;
  float* s2 = ws + 4882496;
  float* sc = ws + 4882560;
  float* sh = ws + 4882624;
  float* out = (float*)d_out;

  // s1 and s2 are contiguous: clear both (ws is poisoned 0xAA before launch)
  hipMemsetAsync(s1, 0, 2 * 64 * sizeof(float), stream);

  prep_kernel<<<512, 256, 0, stream>>>(x, W, y, z, xx);
  knn_kernel<<<ROWS / 4, 256, 0, stream>>>(x, xx, idxp);
  stats_kernel<<<512, 256, 0, stream>>>(y, z, idxp, s1, s2);
  finalize_kernel<<<1, 64, 0, stream>>>(s1, s2, gamma, beta, sc, sh);
  out_kernel<<<512, 256, 0, stream>>>(y, z, idxp, sc, sh, out);
}

// Round 2
// 711.500 us; speedup vs baseline: 1.7665x; 1.7665x over previous
//
#include <hip/hip_runtime.h>
#include <hip/hip_bf16.h>

#define B_ 8
#define C_ 64
#define N_ 4096
#define K_ 20
#define O_ 64

constexpr float BN_EPS = 1e-5f;
constexpr float NEG = 0.2f;
constexpr int ROWS = B_ * N_;        // 32768
constexpr int M_TOT = ROWS * K_;     // 655360
constexpr int RT = 8;                // rows per wave in knn

// ----------------------------------------------------------------------------
// ws layout (float elements):
//   y   : [0,        2097152)   y[b][n][o]  = xt[b,n,:]  . W1[o,:]
//   z   : [2097152,  4194304)   z[b][n][o]  = xt[b,n,:]  . (W2-W1)[o,:]
//   xx  : [4194304,  4227072)   xx[b][n]    = ||xt[b,n,:]||^2
//   idx : [4227072,  4882432)   (int) idx[b][n][k]
//   s1  : [4882432,  4882496)   sum h   per o
//   s2  : [4882496,  4882560)   sum h^2 per o
//   sc  : [4882560,  4882624)   BN scale per o
//   sh  : [4882624,  4882688)   BN shift per o
// ----------------------------------------------------------------------------

__global__ __launch_bounds__(256) void prep_kernel(const float* __restrict__ x,
                                                   const float* __restrict__ W,
                                                   float* __restrict__ y,
                                                   float* __restrict__ z,
                                                   float* __restrict__ xx) {
  __shared__ float xt[64][65];  // [n_local][c]
  __shared__ float w1[64][65];  // [o][c]   = W[o][c]
  __shared__ float wd[64][65];  // [o][c]   = W[o][64+c] - W[o][c]
  const int b = blockIdx.x >> 6;
  const int n0 = (blockIdx.x & 63) << 6;
  const int tid = threadIdx.x;

  for (int rep = 0; rep < 16; ++rep) {
    int id = rep * 256 + tid;
    int cc = id >> 6, nl = id & 63;
    xt[nl][cc] = x[((b * 64 + cc) << 12) + n0 + nl];  // coalesced over nl
    int o = cc, c = nl;
    float a = W[o * 128 + c];
    float bb = W[o * 128 + 64 + c];
    w1[o][c] = a;
    wd[o][c] = bb - a;
  }
  __syncthreads();

  const int o = tid & 63;
  for (int nl = tid >> 6; nl < 64; nl += 4) {
    float ay = 0.f, az = 0.f;
#pragma unroll 8
    for (int c = 0; c < 64; ++c) {
      float v = xt[nl][c];
      ay = fmaf(v, w1[o][c], ay);
      az = fmaf(v, wd[o][c], az);
    }
    int gi = (((b << 12) + n0 + nl) << 6) + o;
    y[gi] = ay;
    z[gi] = az;
  }
  if (tid < 64) {
    float s = 0.f;
#pragma unroll 8
    for (int c = 0; c < 64; ++c) {
      float v = xt[tid][c];
      s = fmaf(v, v, s);
    }
    xx[(b << 12) + tid + n0] = s;
  }
}

// knn v2: 8 rows per wave (amortizes the xj stream 8x through L1),
// sorted-lane top-20 buffer (cheap inserts: 1 ballot + shift-by-1 + bcast).
// Distance v = xx[j] - 2*<xi,xj> with identical FMA chain order to v1
// -> identical neighbor sets.
__global__ __launch_bounds__(256) void knn_kernel(const float* __restrict__ x,
                                                  const float* __restrict__ xx,
                                                  int* __restrict__ idx) {
  const int w = threadIdx.x >> 6;
  const int lane = threadIdx.x & 63;
  const int wave_g = blockIdx.x * 4 + w;
  const int row0 = wave_g * RT;       // 8 consecutive rows, same batch
  const int b = row0 >> 12;
  const int i0 = row0 & 4095;
  const float* xb = x + ((size_t)b << 18);  // b*64*4096

  __shared__ float xi[4][64][RT];  // [wave][c][r], broadcast-read in hot loop

  {
    const float* xp = xb + ((size_t)lane << 12) + i0;  // c = lane
    float4 a0 = *(const float4*)(xp);
    float4 a1 = *(const float4*)(xp + 4);
    *(float4*)&xi[w][lane][0] = a0;
    *(float4*)&xi[w][lane][4] = a1;
  }
  __syncthreads();

  float bv[RT], T[RT];
  int bi[RT];
#pragma unroll
  for (int r = 0; r < RT; ++r) {
    bv[r] = __builtin_inff();
    T[r] = __builtin_inff();
    bi[r] = 0;
  }

  const float* xxb = xx + (b << 12);

  for (int jb = 0; jb < N_; jb += 256) {
    const int j0 = jb + (lane << 2);
    float4 acc[RT];
#pragma unroll
    for (int r = 0; r < RT; ++r) acc[r] = make_float4(0.f, 0.f, 0.f, 0.f);
    const float* xp = xb + j0;
#pragma unroll 4
    for (int c = 0; c < 64; ++c) {
      float4 xj = *(const float4*)(xp + ((size_t)c << 12));
      float4 xa = *(const float4*)&xi[w][c][0];  // same-addr broadcast
      float4 xb4 = *(const float4*)&xi[w][c][4];
      acc[0].x = fmaf(xa.x, xj.x, acc[0].x);
      acc[0].y = fmaf(xa.x, xj.y, acc[0].y);
      acc[0].z = fmaf(xa.x, xj.z, acc[0].z);
      acc[0].w = fmaf(xa.x, xj.w, acc[0].w);
      acc[1].x = fmaf(xa.y, xj.x, acc[1].x);
      acc[1].y = fmaf(xa.y, xj.y, acc[1].y);
      acc[1].z = fmaf(xa.y, xj.z, acc[1].z);
      acc[1].w = fmaf(xa.y, xj.w, acc[1].w);
      acc[2].x = fmaf(xa.z, xj.x, acc[2].x);
      acc[2].y = fmaf(xa.z, xj.y, acc[2].y);
      acc[2].z = fmaf(xa.z, xj.z, acc[2].z);
      acc[2].w = fmaf(xa.z, xj.w, acc[2].w);
      acc[3].x = fmaf(xa.w, xj.x, acc[3].x);
      acc[3].y = fmaf(xa.w, xj.y, acc[3].y);
      acc[3].z = fmaf(xa.w, xj.z, acc[3].z);
      acc[3].w = fmaf(xa.w, xj.w, acc[3].w);
      acc[4].x = fmaf(xb4.x, xj.x, acc[4].x);
      acc[4].y = fmaf(xb4.x, xj.y, acc[4].y);
      acc[4].z = fmaf(xb4.x, xj.z, acc[4].z);
      acc[4].w = fmaf(xb4.x, xj.w, acc[4].w);
      acc[5].x = fmaf(xb4.y, xj.x, acc[5].x);
      acc[5].y = fmaf(xb4.y, xj.y, acc[5].y);
      acc[5].z = fmaf(xb4.y, xj.z, acc[5].z);
      acc[5].w = fmaf(xb4.y, xj.w, acc[5].w);
      acc[6].x = fmaf(xb4.z, xj.x, acc[6].x);
      acc[6].y = fmaf(xb4.z, xj.y, acc[6].y);
      acc[6].z = fmaf(xb4.z, xj.z, acc[6].z);
      acc[6].w = fmaf(xb4.z, xj.w, acc[6].w);
      acc[7].x = fmaf(xb4.w, xj.x, acc[7].x);
      acc[7].y = fmaf(xb4.w, xj.y, acc[7].y);
      acc[7].z = fmaf(xb4.w, xj.z, acc[7].z);
      acc[7].w = fmaf(xb4.w, xj.w, acc[7].w);
    }
    float4 xxj = *(const float4*)(xxb + j0);
#pragma unroll
    for (int r = 0; r < RT; ++r) {
      float dv[4] = {xxj.x - 2.f * acc[r].x, xxj.y - 2.f * acc[r].y,
                     xxj.z - 2.f * acc[r].z, xxj.w - 2.f * acc[r].w};
#pragma unroll
      for (int jj = 0; jj < 4; ++jj) {
        float v = dv[jj];
        unsigned long long m = __ballot(v < T[r]);
        while (m) {
          int src = __ffsll(m) - 1;
          m &= m - 1;
          float cv = __shfl(v, src);
          int cj = __shfl(j0 + jj, src);
          if (cv < T[r]) {  // T may have shrunk since the ballot
            unsigned long long le = __ballot(lane < K_ && bv[r] <= cv);
            int pos = __popcll(le);
            float pv = __shfl_up(bv[r], 1);
            int pi = __shfl_up(bi[r], 1);
            if (lane >= pos) {
              bool ins = (lane == pos);
              bv[r] = ins ? cv : pv;
              bi[r] = ins ? cj : pi;
            }
            T[r] = __shfl(bv[r], K_ - 1);
          }
        }
      }
    }
  }
#pragma unroll
  for (int r = 0; r < RT; ++r) {
    if (lane < K_) idx[(row0 + r) * K_ + lane] = bi[r];
  }
}

__global__ __launch_bounds__(256) void stats_kernel(const float* __restrict__ y,
                                                    const float* __restrict__ z,
                                                    const int* __restrict__ idx,
                                                    float* __restrict__ s1,
                                                    float* __restrict__ s2) {
  const int tid = threadIdx.x;
  const int o = tid & 63;
  const int r = tid >> 6;
  const int row0 = blockIdx.x << 6;  // 64 rows per block
  float a1 = 0.f, a2 = 0.f;
  for (int rl = r; rl < 64; rl += 4) {
    const int row = row0 + rl;
    const int b = row >> 12;
    const float zv = z[(row << 6) + o];
    const int* ip = idx + row * K_;
    const float* yb = y + ((size_t)b << 18);
    float s1r = 0.f;
#pragma unroll
    for (int k = 0; k < K_; ++k) {
      int j = ip[k];
      float h = yb[(j << 6) + o] + zv;
      s1r += h;
      a2 = fmaf(h, h, a2);
    }
    a1 += s1r;
  }
  __shared__ float r1[4][64];
  __shared__ float r2[4][64];
  r1[r][o] = a1;
  r2[r][o] = a2;
  __syncthreads();
  if (tid < 64) {
    float t1 = r1[0][tid] + r1[1][tid] + r1[2][tid] + r1[3][tid];
    float t2 = r2[0][tid] + r2[1][tid] + r2[2][tid] + r2[3][tid];
    atomicAdd(&s1[tid], t1);
    atomicAdd(&s2[tid], t2);
  }
}

__global__ void finalize_kernel(const float* __restrict__ s1,
                                const float* __restrict__ s2,
                                const float* __restrict__ gamma,
                                const float* __restrict__ beta,
                                float* __restrict__ sc,
                                float* __restrict__ sh) {
  int o = threadIdx.x;
  float mean = s1[o] / (float)M_TOT;
  float var = s2[o] / (float)M_TOT - mean * mean;
  float inv = 1.0f / sqrtf(var + BN_EPS);
  float s = gamma[o] * inv;
  sc[o] = s;
  sh[o] = beta[o] - mean * s;
}

__global__ __launch_bounds__(256) void out_kernel(const float* __restrict__ y,
                                                  const float* __restrict__ z,
                                                  const int* __restrict__ idx,
                                                  const float* __restrict__ sc,
                                                  const float* __restrict__ sh,
                                                  float* __restrict__ out) {
  __shared__ float til[64][65];  // [o][n_local]
  const int tid = threadIdx.x;
  const int b = blockIdx.x >> 6;
  const int n0 = (blockIdx.x & 63) << 6;
  const int o = tid & 63;
  const float s = sc[o];
  const float t = sh[o];
  const float* yb = y + ((size_t)b << 18);

  for (int nl = tid >> 6; nl < 64; nl += 4) {
    const int row = (b << 12) + n0 + nl;
    const float zv = z[(row << 6) + o];
    const int* ip = idx + row * K_;
    float m = -__builtin_inff();
#pragma unroll
    for (int k = 0; k < K_; ++k) {
      int j = ip[k];
      float h = yb[(j << 6) + o] + zv;
      float hn = fmaf(h, s, t);
      float a = hn >= 0.f ? hn : NEG * hn;
      m = fmaxf(m, a);
    }
    til[o][nl] = m;
  }
  __syncthreads();
  for (int rep = 0; rep < 16; ++rep) {
    int id = rep * 256 + tid;
    int oo = id >> 6, nl = id & 63;
    out[((size_t)((b << 6) + oo) << 12) + n0 + nl] = til[oo][nl];
  }
}

extern "C" void kernel_launch(void* const* d_in, const int* in_sizes, int n_in,
                              void* d_out, int out_size, void* d_ws, size_t ws_size,
                              hipStream_t stream) {
  const float* x = (const float*)d_in[0];
  const float* W = (const float*)d_in[1];
  const float* gamma = (const float*)d_in[2];
  const float* beta = (const float*)d_in[3];
  float* ws = (float*)d_ws;
  float* y = ws;
  float* z = ws + 2097152;
  float* xx = ws + 4194304;
  int* idxp = (int*)(ws + 4227072);
  float* s1 = ws + 4882432;
  float* s2 = ws + 4882496;
  float* sc = ws + 4882560;
  float* sh = ws + 4882624;
  float* out = (float*)d_out;

  hipMemsetAsync(s1, 0, 2 * 64 * sizeof(float), stream);

  prep_kernel<<<512, 256, 0, stream>>>(x, W, y, z, xx);
  knn_kernel<<<ROWS / (4 * RT), 256, 0, stream>>>(x, xx, idxp);
  stats_kernel<<<512, 256, 0, stream>>>(y, z, idxp, s1, s2);
  finalize_kernel<<<1, 64, 0, stream>>>(s1, s2, gamma, beta, sc, sh);
  out_kernel<<<512, 256, 0, stream>>>(y, z, idxp, sc, sh, out);
}

// Round 3
// 638.618 us; speedup vs baseline: 1.9681x; 1.1141x over previous
//
#include <hip/hip_runtime.h>
#include <hip/hip_bf16.h>

#define B_ 8
#define C_ 64
#define N_ 4096
#define K_ 20
#define O_ 64

constexpr float BN_EPS = 1e-5f;
constexpr float NEG = 0.2f;
constexpr int ROWS = B_ * N_;        // 32768
constexpr int M_TOT = ROWS * K_;     // 655360
constexpr int RT = 8;                // rows per wave in knn

// ----------------------------------------------------------------------------
// ws layout (float elements):
//   y   : [0,        2097152)   y[b][n][o]  = xt[b,n,:]  . W1[o,:]
//   z   : [2097152,  4194304)   z[b][n][o]  = xt[b,n,:]  . (W2-W1)[o,:]
//   xx  : [4194304,  4227072)   xx[b][n]    = ||xt[b,n,:]||^2
//   idx : [4227072,  4882432)   (int) idx[b][n][k]
//   s1/s2/sc/sh : 64 floats each after that
// ----------------------------------------------------------------------------

__global__ __launch_bounds__(256) void prep_kernel(const float* __restrict__ x,
                                                   const float* __restrict__ W,
                                                   float* __restrict__ y,
                                                   float* __restrict__ z,
                                                   float* __restrict__ xx) {
  __shared__ float xt[64][65];  // [n_local][c]
  __shared__ float w1[64][65];  // [o][c]   = W[o][c]
  __shared__ float wd[64][65];  // [o][c]   = W[o][64+c] - W[o][c]
  const int b = blockIdx.x >> 6;
  const int n0 = (blockIdx.x & 63) << 6;
  const int tid = threadIdx.x;

  for (int rep = 0; rep < 16; ++rep) {
    int id = rep * 256 + tid;
    int cc = id >> 6, nl = id & 63;
    xt[nl][cc] = x[((b * 64 + cc) << 12) + n0 + nl];  // coalesced over nl
    int o = cc, c = nl;
    float a = W[o * 128 + c];
    float bb = W[o * 128 + 64 + c];
    w1[o][c] = a;
    wd[o][c] = bb - a;
  }
  __syncthreads();

  const int o = tid & 63;
  for (int nl = tid >> 6; nl < 64; nl += 4) {
    float ay = 0.f, az = 0.f;
#pragma unroll 8
    for (int c = 0; c < 64; ++c) {
      float v = xt[nl][c];
      ay = fmaf(v, w1[o][c], ay);
      az = fmaf(v, wd[o][c], az);
    }
    int gi = (((b << 12) + n0 + nl) << 6) + o;
    y[gi] = ay;
    z[gi] = az;
  }
  if (tid < 64) {
    float s = 0.f;
#pragma unroll 8
    for (int c = 0; c < 64; ++c) {
      float v = xt[tid][c];
      s = fmaf(v, v, s);
    }
    xx[(b << 12) + n0 + tid] = s;
  }
}

// knn v3: 128-thread blocks (2 waves) for finer residency packing, JQ=2
// (2 j's per lane -> acc=float2[8], ~60 VGPR), unroll-8 c-loop for deep
// load pipelining, trimmed insert chain. Distance FMA chain order is
// bit-identical to v2 -> identical neighbor sets.
__global__ __launch_bounds__(128, 4) void knn_kernel(const float* __restrict__ x,
                                                     const float* __restrict__ xx,
                                                     int* __restrict__ idx) {
  const int w = threadIdx.x >> 6;      // 0..1
  const int lane = threadIdx.x & 63;
  const int wave_g = blockIdx.x * 2 + w;
  const int row0 = wave_g * RT;        // 8 consecutive rows, same batch
  const int b = row0 >> 12;
  const int i0 = row0 & 4095;
  const float* xb = x + ((size_t)b << 18);  // b*64*4096

  __shared__ float xi[2][64][RT];  // [wave][c][r], broadcast-read in hot loop

  {
    const float* xp = xb + ((size_t)lane << 12) + i0;  // c = lane
    float4 a0 = *(const float4*)(xp);
    float4 a1 = *(const float4*)(xp + 4);
    *(float4*)&xi[w][lane][0] = a0;
    *(float4*)&xi[w][lane][4] = a1;
  }
  __syncthreads();

  float bv[RT], T[RT];
  int bi[RT];
#pragma unroll
  for (int r = 0; r < RT; ++r) {
    bv[r] = __builtin_inff();
    T[r] = __builtin_inff();
    bi[r] = 0;
  }

  const float* xxb = xx + (b << 12);

  for (int jb = 0; jb < N_; jb += 128) {
    const int j0 = jb + (lane << 1);
    float2 acc[RT];
#pragma unroll
    for (int r = 0; r < RT; ++r) acc[r] = make_float2(0.f, 0.f);
    const float* xp = xb + j0;
#pragma unroll 8
    for (int c = 0; c < 64; ++c) {
      float2 xj = *(const float2*)(xp + ((size_t)c << 12));
      float4 xa = *(const float4*)&xi[w][c][0];   // same-addr broadcast
      float4 xc = *(const float4*)&xi[w][c][4];
      acc[0].x = fmaf(xa.x, xj.x, acc[0].x);
      acc[0].y = fmaf(xa.x, xj.y, acc[0].y);
      acc[1].x = fmaf(xa.y, xj.x, acc[1].x);
      acc[1].y = fmaf(xa.y, xj.y, acc[1].y);
      acc[2].x = fmaf(xa.z, xj.x, acc[2].x);
      acc[2].y = fmaf(xa.z, xj.y, acc[2].y);
      acc[3].x = fmaf(xa.w, xj.x, acc[3].x);
      acc[3].y = fmaf(xa.w, xj.y, acc[3].y);
      acc[4].x = fmaf(xc.x, xj.x, acc[4].x);
      acc[4].y = fmaf(xc.x, xj.y, acc[4].y);
      acc[5].x = fmaf(xc.y, xj.x, acc[5].x);
      acc[5].y = fmaf(xc.y, xj.y, acc[5].y);
      acc[6].x = fmaf(xc.z, xj.x, acc[6].x);
      acc[6].y = fmaf(xc.z, xj.y, acc[6].y);
      acc[7].x = fmaf(xc.w, xj.x, acc[7].x);
      acc[7].y = fmaf(xc.w, xj.y, acc[7].y);
    }
    float2 xxj = *(const float2*)(xxb + j0);
#pragma unroll
    for (int r = 0; r < RT; ++r) {
      float dv[2] = {xxj.x - 2.f * acc[r].x, xxj.y - 2.f * acc[r].y};
#pragma unroll
      for (int jj = 0; jj < 2; ++jj) {
        float v = dv[jj];
        unsigned long long m = __ballot(v < T[r]);
        while (m) {
          int src = __ffsll(m) - 1;
          m &= m - 1;
          float cv = __shfl(v, src);
          int cj = __shfl(j0 + jj, src);
          if (cv < T[r]) {  // T may have shrunk since the ballot
            // lanes >= 20 masked arithmetically; bv starts +inf everywhere
            unsigned long long le = __ballot(bv[r] <= cv) & 0xFFFFFull;
            int pos = __popcll(le);
            float pv = __shfl_up(bv[r], 1);
            int pi = __shfl_up(bi[r], 1);
            if (lane >= pos) {
              bool ins = (lane == pos);
              bv[r] = ins ? cv : pv;
              bi[r] = ins ? cj : pi;
            }
            T[r] = __shfl(bv[r], K_ - 1);
          }
        }
      }
    }
  }
#pragma unroll
  for (int r = 0; r < RT; ++r) {
    if (lane < K_) idx[(row0 + r) * K_ + lane] = bi[r];
  }
}

__global__ __launch_bounds__(256) void stats_kernel(const float* __restrict__ y,
                                                    const float* __restrict__ z,
                                                    const int* __restrict__ idx,
                                                    float* __restrict__ s1,
                                                    float* __restrict__ s2) {
  const int tid = threadIdx.x;
  const int o = tid & 63;
  const int r = tid >> 6;
  const int row0 = blockIdx.x << 6;  // 64 rows per block
  float a1 = 0.f, a2 = 0.f;
  for (int rl = r; rl < 64; rl += 4) {
    const int row = row0 + rl;
    const int b = row >> 12;
    const float zv = z[(row << 6) + o];
    const int* ip = idx + row * K_;
    const float* yb = y + ((size_t)b << 18);
    float s1r = 0.f;
#pragma unroll
    for (int k = 0; k < K_; ++k) {
      int j = ip[k];
      float h = yb[(j << 6) + o] + zv;
      s1r += h;
      a2 = fmaf(h, h, a2);
    }
    a1 += s1r;
  }
  __shared__ float r1[4][64];
  __shared__ float r2[4][64];
  r1[r][o] = a1;
  r2[r][o] = a2;
  __syncthreads();
  if (tid < 64) {
    float t1 = r1[0][tid] + r1[1][tid] + r1[2][tid] + r1[3][tid];
    float t2 = r2[0][tid] + r2[1][tid] + r2[2][tid] + r2[3][tid];
    atomicAdd(&s1[tid], t1);
    atomicAdd(&s2[tid], t2);
  }
}

__global__ void finalize_kernel(const float* __restrict__ s1,
                                const float* __restrict__ s2,
                                const float* __restrict__ gamma,
                                const float* __restrict__ beta,
                                float* __restrict__ sc,
                                float* __restrict__ sh) {
  int o = threadIdx.x;
  float mean = s1[o] / (float)M_TOT;
  float var = s2[o] / (float)M_TOT - mean * mean;
  float inv = 1.0f / sqrtf(var + BN_EPS);
  float s = gamma[o] * inv;
  sc[o] = s;
  sh[o] = beta[o] - mean * s;
}

__global__ __launch_bounds__(256) void out_kernel(const float* __restrict__ y,
                                                  const float* __restrict__ z,
                                                  const int* __restrict__ idx,
                                                  const float* __restrict__ sc,
                                                  const float* __restrict__ sh,
                                                  float* __restrict__ out) {
  __shared__ float til[64][65];  // [o][n_local]
  const int tid = threadIdx.x;
  const int b = blockIdx.x >> 6;
  const int n0 = (blockIdx.x & 63) << 6;
  const int o = tid & 63;
  const float s = sc[o];
  const float t = sh[o];
  const float* yb = y + ((size_t)b << 18);

  for (int nl = tid >> 6; nl < 64; nl += 4) {
    const int row = (b << 12) + n0 + nl;
    const float zv = z[(row << 6) + o];
    const int* ip = idx + row * K_;
    float m = -__builtin_inff();
#pragma unroll
    for (int k = 0; k < K_; ++k) {
      int j = ip[k];
      float h = yb[(j << 6) + o] + zv;
      float hn = fmaf(h, s, t);
      float a = hn >= 0.f ? hn : NEG * hn;
      m = fmaxf(m, a);
    }
    til[o][nl] = m;
  }
  __syncthreads();
  for (int rep = 0; rep < 16; ++rep) {
    int id = rep * 256 + tid;
    int oo = id >> 6, nl = id & 63;
    out[((size_t)((b << 6) + oo) << 12) + n0 + nl] = til[oo][nl];
  }
}

extern "C" void kernel_launch(void* const* d_in, const int* in_sizes, int n_in,
                              void* d_out, int out_size, void* d_ws, size_t ws_size,
                              hipStream_t stream) {
  const float* x = (const float*)d_in[0];
  const float* W = (const float*)d_in[1];
  const float* gamma = (const float*)d_in[2];
  const float* beta = (const float*)d_in[3];
  float* ws = (float*)d_ws;
  float* y = ws;
  float* z = ws + 2097152;
  float* xx = ws + 4194304;
  int* idxp = (int*)(ws + 4227072);
  float* s1 = ws + 4882432;
  float* s2 = ws + 4882496;
  float* sc = ws + 4882560;
  float* sh = ws + 4882624;
  float* out = (float*)d_out;

  hipMemsetAsync(s1, 0, 2 * 64 * sizeof(float), stream);

  prep_kernel<<<512, 256, 0, stream>>>(x, W, y, z, xx);
  knn_kernel<<<ROWS / (2 * RT), 128, 0, stream>>>(x, xx, idxp);
  stats_kernel<<<512, 256, 0, stream>>>(y, z, idxp, s1, s2);
  finalize_kernel<<<1, 64, 0, stream>>>(s1, s2, gamma, beta, sc, sh);
  out_kernel<<<512, 256, 0, stream>>>(y, z, idxp, sc, sh, out);
}